// Round 2
// baseline (4863.474 us; speedup 1.0000x reference)
//
#include <hip/hip_runtime.h>
#include <hip/hip_bf16.h>

#define TT 512
#define BB 128
#define II 256
#define HH 512

#define NGROUP 8    // batch groups of 16 rows (group -> XCD affinity via wg&7)
#define WPG    16   // workgroups per group; each WG owns 32 cols (2 col-halves x 2 K-halves)
#define NWG    (NGROUP * WPG)

typedef __attribute__((ext_vector_type(8))) unsigned short ushort8;
typedef __attribute__((ext_vector_type(8))) __bf16        bf16x8;
typedef __attribute__((ext_vector_type(4))) float         float4v;

union frag8 { ushort8 u; bf16x8 b; };

__device__ __forceinline__ unsigned short f2bf(float f) {
    union { float f; unsigned u; } v; v.f = f;
    unsigned r = (v.u + 0x7FFFu + ((v.u >> 16) & 1u)) >> 16;  // RNE
    return (unsigned short)r;
}
__device__ __forceinline__ float bf2f(unsigned short h) {
    union { unsigned u; float f; } v; v.u = ((unsigned)h) << 16;
    return v.f;
}
__device__ __forceinline__ float tanh_fast(float x) {
    float e = __expf(2.0f * x);          // robust at +-large: -> 1 / -1
    return 1.0f - 2.0f / (e + 1.0f);
}
__device__ __forceinline__ float4v mfma(bf16x8 a, bf16x8 b, float4v c) {
    return __builtin_amdgcn_mfma_f32_16x16x32_bf16(a, b, c, 0, 0, 0);
}

__global__ __launch_bounds__(256, 1) void rnn_fused(
    const float* __restrict__ Xt,   // [T][B][I]
    const float* __restrict__ W1,   // [768][512]
    const float* __restrict__ b1,   // [512]
    const float* __restrict__ W2,   // [1024][512]
    const float* __restrict__ b2,   // [512]
    float* __restrict__ out,        // [T][B][H] ++ [2][B][H]
    unsigned short* __restrict__ Ybuf,  // Y1[2][B*H] then Y2[2][B*H], bf16 bits
    unsigned int* __restrict__ cnt)     // [NGROUP][1024] per-step arrival counters
{
    const int wg  = blockIdx.x;
    const int g   = wg & 7;        // batch group (XCD affinity heuristic)
    const int j   = wg >> 3;       // 0..15: 32-col block
    const int tid = threadIdx.x;
    const int w   = tid >> 6;
    const int c   = w & 1;         // col half: 16 cols
    const int kh  = w >> 1;        // K half
    const int l   = tid & 63;
    const int lr  = l & 15;        // fragment row/col index
    const int lq  = l >> 4;        // k-chunk / row-quad selector
    const int n0  = j * 32 + c * 16;
    const int row0 = g * 16;

    unsigned short* Y1 = Ybuf;
    unsigned short* Y2 = Ybuf + 2 * BB * HH;

    __shared__ float lds[2][2][64][4];  // [layer][c][lane][reg] partial sums from kh=1

    // ---- persistent weight fragments, hi + lo bf16 split ----
    // B-frag: lane l holds B[k = 32q + lq*8 + e][n0 + lr]
    // kh=0: W1 rows 0..383 (x + h1[0:128]),  W2 rows 0..511   (y1 part)
    // kh=1: W1 rows 384..767 (h1[128:512]),  W2 rows 512..1023 (h2 part)
    frag8 w1h[12], w1l[12], w2h[16], w2l[16];
    const int kb1 = kh * 12, kb2 = kh * 16;
#pragma unroll
    for (int q = 0; q < 12; ++q) {
#pragma unroll
        for (int e = 0; e < 8; ++e) {
            float v = W1[((kb1 + q) * 32 + lq * 8 + e) * HH + n0 + lr];
            unsigned short hi = f2bf(v);
            w1h[q].u[e] = hi;
            w1l[q].u[e] = f2bf(v - bf2f(hi));
        }
    }
#pragma unroll
    for (int q = 0; q < 16; ++q) {
#pragma unroll
        for (int e = 0; e < 8; ++e) {
            float v = W2[((kb2 + q) * 32 + lq * 8 + e) * HH + n0 + lr];
            unsigned short hi = f2bf(v);
            w2h[q].u[e] = hi;
            w2l[q].u[e] = f2bf(v - bf2f(hi));
        }
    }
    const float bias1 = (kh == 0) ? b1[n0 + lr] : 0.0f;
    const float bias2 = (kh == 0) ? b2[n0 + lr] : 0.0f;

    // Pipelined: interval t computes y1(t) [layer1] and y2(t-1) [layer2];
    // both depend only on data sealed by group-barrier t-1.
#pragma unroll 1
    for (int t = 0; t <= TT; ++t) {
        const int par = t & 1;
        const unsigned short* y1r = Y1 + (par ^ 1) * (BB * HH);  // y1(t-1)
        const unsigned short* y2r = Y2 + par * (BB * HH);        // y2(t-2)

        frag8 a1[16];  // A-frags of y1(t-1): lane l holds A[row0+lr][32q + lq*8 + e]
#pragma unroll
        for (int q = 0; q < 16; ++q)
            a1[q].u = *(const ushort8*)(y1r + (row0 + lr) * HH + q * 32 + lq * 8);

        float4v acc1 = {bias1, bias1, bias1, bias1};
        float4v acc2 = {bias2, bias2, bias2, bias2};

        if (kh == 0) {
            if (t < TT) {  // L1 partial: x(t) (k 0..255) + h1 frags 0..3 (k 256..383)
#pragma unroll
                for (int q = 0; q < 8; ++q) {
                    const float* xp = Xt + ((size_t)t * BB + row0 + lr) * II + q * 32 + lq * 8;
                    frag8 ax;
#pragma unroll
                    for (int e = 0; e < 8; ++e) ax.u[e] = f2bf(xp[e]);
                    acc1 = mfma(ax.b, w1h[q].b, acc1);
                    acc1 = mfma(ax.b, w1l[q].b, acc1);
                }
#pragma unroll
                for (int q = 0; q < 4; ++q) {
                    acc1 = mfma(a1[q].b, w1h[8 + q].b, acc1);
                    acc1 = mfma(a1[q].b, w1l[8 + q].b, acc1);
                }
            }
            if (t >= 1) {  // L2 partial: y1(t-1) over k 0..511
#pragma unroll
                for (int q = 0; q < 16; ++q) {
                    acc2 = mfma(a1[q].b, w2h[q].b, acc2);
                    acc2 = mfma(a1[q].b, w2l[q].b, acc2);
                }
            }
        } else {
            if (t < TT) {  // L1 partial: h1 frags 4..15 (k 384..767)
#pragma unroll
                for (int q = 0; q < 12; ++q) {
                    acc1 = mfma(a1[4 + q].b, w1h[q].b, acc1);
                    acc1 = mfma(a1[4 + q].b, w1l[q].b, acc1);
                }
            }
            if (t >= 1) {  // L2 partial: y2(t-2) over k 512..1023
                frag8 a2[16];
#pragma unroll
                for (int q = 0; q < 16; ++q)
                    a2[q].u = *(const ushort8*)(y2r + (row0 + lr) * HH + q * 32 + lq * 8);
#pragma unroll
                for (int q = 0; q < 16; ++q) {
                    acc2 = mfma(a2[q].b, w2h[q].b, acc2);
                    acc2 = mfma(a2[q].b, w2l[q].b, acc2);
                }
            }
            *(float4v*)&lds[0][c][l][0] = acc1;
            *(float4v*)&lds[1][c][l][0] = acc2;
        }
        __syncthreads();  // kh=1 partials visible in LDS

        if (kh == 0) {
            // C/D layout: lane l reg i -> row = lq*4 + i, col = lr
            float4v p1 = *(const float4v*)&lds[0][c][l][0];
            float4v p2 = *(const float4v*)&lds[1][c][l][0];
            if (t < TT) {
                unsigned short* y1w = Y1 + par * (BB * HH);
#pragma unroll
                for (int i = 0; i < 4; ++i) {
                    float y = tanh_fast(acc1[i] + p1[i]);
                    int r = row0 + lq * 4 + i;
                    y1w[r * HH + n0 + lr] = f2bf(y);
                    if (t == TT - 1)  // hidden[0] = final h1
                        out[(size_t)TT * BB * HH + (size_t)r * HH + n0 + lr] = y;
                }
            }
            if (t >= 1) {
                unsigned short* y2w = Y2 + (par ^ 1) * (BB * HH);
#pragma unroll
                for (int i = 0; i < 4; ++i) {
                    float y = tanh_fast(acc2[i] + p2[i]);
                    int r = row0 + lq * 4 + i;
                    y2w[r * HH + n0 + lr] = f2bf(y);
                    out[((size_t)(t - 1) * BB + r) * HH + n0 + lr] = y;
                    if (t == TT)  // hidden[1] = final h2
                        out[(size_t)TT * BB * HH + (size_t)BB * HH + (size_t)r * HH + n0 + lr] = y;
                }
            }
        }

        // ---- group barrier (16 WGs), one per interval ----
        if (t < TT) {
            __syncthreads();  // all waves' global stores drained (vmcnt 0) before flag
            if (tid == 0) {
                unsigned int* cp = cnt + g * 1024 + t;
                __hip_atomic_fetch_add(cp, 1u, __ATOMIC_RELEASE, __HIP_MEMORY_SCOPE_AGENT);
                while (__hip_atomic_load(cp, __ATOMIC_RELAXED, __HIP_MEMORY_SCOPE_AGENT) < WPG)
                    __builtin_amdgcn_s_sleep(2);
                __builtin_amdgcn_fence(__ATOMIC_ACQUIRE, "agent");
            }
            __syncthreads();
        }
    }
}

extern "C" void kernel_launch(void* const* d_in, const int* in_sizes, int n_in,
                              void* d_out, int out_size, void* d_ws, size_t ws_size,
                              hipStream_t stream) {
    const float* Xt = (const float*)d_in[0];
    const float* W1 = (const float*)d_in[1];
    const float* b1 = (const float*)d_in[2];
    const float* W2 = (const float*)d_in[3];
    const float* b2 = (const float*)d_in[4];
    float* out = (float*)d_out;

    unsigned short* Ybuf = (unsigned short*)d_ws;                    // 4*128*512*2B = 512 KB
    unsigned int*   cnt  = (unsigned int*)((char*)d_ws + 4 * BB * HH * 2);
    size_t zero_bytes = (size_t)4 * BB * HH * 2 + (size_t)NGROUP * 1024 * 4;

    hipMemsetAsync(d_ws, 0, zero_bytes, stream);  // zero exchange buffers + barrier counters
    hipLaunchKernelGGL(rnn_fused, dim3(NWG), dim3(256), 0, stream,
                       Xt, W1, b1, W2, b2, out, Ybuf, cnt);
}